// Round 3
// baseline (1104.424 us; speedup 1.0000x reference)
//
#include <hip/hip_runtime.h>
#include <hip/hip_bf16.h>

// B=64, T=60 (40 enc + 20 dec), H=512, E=512, V=32000.
// DTYPE (round-2 post-mortem): inputs/output are fp32 per the reference
// ("bf16" in the harness label is hard-coded). Compute uses bf16 MFMA with
// on-the-fly fp32->bf16 (RNE) conversion in the LDS staging loaders; fp32
// accumulate; Xp / c / biases / logits stay fp32; h / dec_h are bf16.
//
// Memory plan:
//   d_ws (1.5 MB): h0, h1, c, dec_h
//   d_out (155.6 MB fp32): first 31.5 MB doubles as fp32 X_proj scratch;
//         X_proj is dead before GEMM2 overwrites d_out with logits.
//
// Pipeline:
//   1) gemm_xproj: Xp[3840][2048] = xs @ W_ih^T + (b_ih+b_hh); xs built on the
//      fly (zero-pad | embedding gather | feature).
//   2) 59x lstm_step: gates = Xp[t] + h @ W_hh^T; cell update; h ping-pong.
//   3) gemm_bt: out[1216][32000] = dec_h @ W_lin^T + b_lin, fp32 out.

typedef short bf16x8 __attribute__((ext_vector_type(8)));
typedef float f32x4 __attribute__((ext_vector_type(4)));

__device__ inline short f2bf(float f) {
    unsigned u = __float_as_uint(f);
    unsigned r = (u + 0x7fffu + ((u >> 16) & 1u)) >> 16;   // RNE
    return (short)r;
}
// load 8 fp32 from g, round to bf16, return packed 16B
__device__ inline int4 ld8_f32_to_bf16(const float* __restrict__ g) {
    float4 a = *(const float4*)g;
    float4 b = *(const float4*)(g + 4);
    union { short s[8]; int4 v; } u;
    u.s[0] = f2bf(a.x); u.s[1] = f2bf(a.y); u.s[2] = f2bf(a.z); u.s[3] = f2bf(a.w);
    u.s[4] = f2bf(b.x); u.s[5] = f2bf(b.y); u.s[6] = f2bf(b.z); u.s[7] = f2bf(b.w);
    return u.v;
}
__device__ inline float sigf(float x) { return 1.0f / (1.0f + expf(-x)); }

// ---------------------------------------------------------------------------
// GEMM1 (fused xs build): Xp[3840][2048] = xs @ W_ih^T + (b_ih + b_hh), fp32.
// Block 256 thr, tile 128x128, BK=64. LDS stride 72 shorts breaks conflicts.
// A row = t*64+b; A col j: j<512 -> (t<40 ? 0 : emb[captions[b][t-40]][j]),
//                          else  -> feature[b][t][j-512].
// ---------------------------------------------------------------------------
__global__ __launch_bounds__(256) void gemm_xproj(
    const float* __restrict__ feature,    // [64][60][512] f32
    const int*   __restrict__ captions,   // [64][20]
    const float* __restrict__ embedding,  // [32000][512] f32
    const float* __restrict__ W_ih,       // [2048][1024] f32
    const float* __restrict__ b_ih,       // [2048] f32
    const float* __restrict__ b_hh,       // [2048] f32
    float* __restrict__ Xp)               // [3840][2048] f32
{
    __shared__ __align__(16) short Al[128 * 72];
    __shared__ __align__(16) short Bl[128 * 72];
    const int tid  = threadIdx.x;
    const int wave = tid >> 6, lane = tid & 63;
    const int quad = lane >> 4, l16 = lane & 15;
    const int m0 = blockIdx.y * 128;
    const int n0 = blockIdx.x * 128;
    const int wm = (wave >> 1) * 64, wn = (wave & 1) * 64;
    const int sr = tid >> 3;            // 0..31
    const int sc = (tid & 7) * 8;       // 0..56

    f32x4 acc[4][4] = {};

    for (int k0 = 0; k0 < 1024; k0 += 64) {
        const int j = k0 + sc;          // [k0, k0+63]: never straddles 512
#pragma unroll
        for (int p = 0; p < 4; ++p) {
            int r = sr + p * 32;
            int row = m0 + r;
            int t = row >> 6, b = row & 63;
            int4 val;
            if (j < 512) {
                if (t >= 40) {
                    int tok = captions[b * 20 + (t - 40)];
                    val = ld8_f32_to_bf16(&embedding[(size_t)tok * 512 + j]);
                } else {
                    val = make_int4(0, 0, 0, 0);
                }
            } else {
                val = ld8_f32_to_bf16(&feature[(size_t)(b * 60 + t) * 512 + (j - 512)]);
            }
            *(int4*)&Al[r * 72 + sc] = val;
            *(int4*)&Bl[r * 72 + sc] = ld8_f32_to_bf16(&W_ih[(size_t)(n0 + r) * 1024 + j]);
        }
        __syncthreads();
#pragma unroll
        for (int kk = 0; kk < 64; kk += 32) {
            bf16x8 af[4], bg[4];
#pragma unroll
            for (int i = 0; i < 4; ++i)
                af[i] = *(const bf16x8*)&Al[(wm + i * 16 + l16) * 72 + kk + quad * 8];
#pragma unroll
            for (int jj = 0; jj < 4; ++jj)
                bg[jj] = *(const bf16x8*)&Bl[(wn + jj * 16 + l16) * 72 + kk + quad * 8];
#pragma unroll
            for (int i = 0; i < 4; ++i)
#pragma unroll
                for (int jj = 0; jj < 4; ++jj)
                    acc[i][jj] = __builtin_amdgcn_mfma_f32_16x16x32_bf16(
                        af[i], bg[jj], acc[i][jj], 0, 0, 0);
        }
        __syncthreads();
    }

    // D layout: row = quad*4 + reg, col = l16 (measured m89/m91)
#pragma unroll
    for (int jj = 0; jj < 4; ++jj) {
        int n = n0 + wn + jj * 16 + l16;
        float bv = b_ih[n] + b_hh[n];
#pragma unroll
        for (int i = 0; i < 4; ++i) {
            int mbase = m0 + wm + i * 16 + quad * 4;
#pragma unroll
            for (int r = 0; r < 4; ++r)
                Xp[(size_t)(mbase + r) * 2048 + n] = acc[i][jj][r] + bv;
        }
    }
}

// ---------------------------------------------------------------------------
// GEMM2: out[M][N] = A[M][K](bf16) @ W[N][K]^T(f32->bf16) + bias(f32),
// fp32 out, M-guard.
// ---------------------------------------------------------------------------
__global__ __launch_bounds__(256) void gemm_bt(
    const short* __restrict__ A,       // M x K bf16
    const float* __restrict__ W,       // N x K f32
    const float* __restrict__ bias,    // N f32
    float* __restrict__ C,
    int M, int N, int K)
{
    __shared__ __align__(16) short Al[128 * 72];
    __shared__ __align__(16) short Bl[128 * 72];
    const int tid  = threadIdx.x;
    const int wave = tid >> 6, lane = tid & 63;
    const int quad = lane >> 4, l16 = lane & 15;
    const int m0 = blockIdx.y * 128;
    const int n0 = blockIdx.x * 128;
    const int wm = (wave >> 1) * 64, wn = (wave & 1) * 64;
    const int sr = tid >> 3;
    const int sc = (tid & 7) * 8;

    f32x4 acc[4][4] = {};

    for (int k0 = 0; k0 < K; k0 += 64) {
#pragma unroll
        for (int p = 0; p < 4; ++p) {
            int r = sr + p * 32;
            int am = m0 + r;
            am = (am < M) ? am : (M - 1);
            *(int4*)&Al[r * 72 + sc] = *(const int4*)&A[(size_t)am * K + k0 + sc];
            *(int4*)&Bl[r * 72 + sc] =
                ld8_f32_to_bf16(&W[(size_t)(n0 + r) * K + k0 + sc]);
        }
        __syncthreads();
#pragma unroll
        for (int kk = 0; kk < 64; kk += 32) {
            bf16x8 af[4], bg[4];
#pragma unroll
            for (int i = 0; i < 4; ++i)
                af[i] = *(const bf16x8*)&Al[(wm + i * 16 + l16) * 72 + kk + quad * 8];
#pragma unroll
            for (int jj = 0; jj < 4; ++jj)
                bg[jj] = *(const bf16x8*)&Bl[(wn + jj * 16 + l16) * 72 + kk + quad * 8];
#pragma unroll
            for (int i = 0; i < 4; ++i)
#pragma unroll
                for (int jj = 0; jj < 4; ++jj)
                    acc[i][jj] = __builtin_amdgcn_mfma_f32_16x16x32_bf16(
                        af[i], bg[jj], acc[i][jj], 0, 0, 0);
        }
        __syncthreads();
    }

#pragma unroll
    for (int jj = 0; jj < 4; ++jj) {
        int n = n0 + wn + jj * 16 + l16;
        float bv = bias[n];
#pragma unroll
        for (int i = 0; i < 4; ++i) {
            int mbase = m0 + wm + i * 16 + quad * 4;
#pragma unroll
            for (int r = 0; r < 4; ++r) {
                int m = mbase + r;
                if (m < M)
                    C[(size_t)m * N + n] = acc[i][jj][r] + bv;
            }
        }
    }
}

// ---------------------------------------------------------------------------
// LSTM step: gates[64][2048] = Xp[t] + h_in @ W_hh^T, then cell update.
// 32 blocks; block -> cols [16*bx, 16*bx+16) of each of the 4 gate sections.
// Wave w -> batch rows 16w..16w+15; accs for i,f,g,o share the (row,col) patch.
// ---------------------------------------------------------------------------
__global__ __launch_bounds__(256) void lstm_step(
    const float* __restrict__ Xp,     // [64][2048] f32 slice for this t
    const float* __restrict__ W_hh,   // [2048][512] f32
    const short* __restrict__ h_in,   // [64][512] bf16
    short* __restrict__ h_out,        // [64][512] bf16
    float* __restrict__ c,            // [64][512] f32
    short* __restrict__ dec_h,        // [1216][512] bf16 (row = b*19 + dec_idx)
    int dec_idx)                      // t-40 (write dec_h iff >= 0)
{
    __shared__ __align__(16) short Al[64 * 72];
    __shared__ __align__(16) short Bl[64 * 72];
    const int tid  = threadIdx.x;
    const int wave = tid >> 6, lane = tid & 63;
    const int quad = lane >> 4, l16 = lane & 15;
    const int nb = blockIdx.x * 16;
    const int sr = tid >> 3, sc = (tid & 7) * 8;

    f32x4 acc[4] = {};

    for (int k0 = 0; k0 < 512; k0 += 64) {
#pragma unroll
        for (int p = 0; p < 2; ++p) {
            int r = sr + p * 32;
            *(int4*)&Al[r * 72 + sc] = *(const int4*)&h_in[r * 512 + k0 + sc];
            int s = r >> 4, ridx = r & 15;
            *(int4*)&Bl[r * 72 + sc] =
                ld8_f32_to_bf16(&W_hh[(size_t)(s * 512 + nb + ridx) * 512 + k0 + sc]);
        }
        __syncthreads();
#pragma unroll
        for (int kk = 0; kk < 64; kk += 32) {
            bf16x8 af = *(const bf16x8*)&Al[(wave * 16 + l16) * 72 + kk + quad * 8];
#pragma unroll
            for (int s = 0; s < 4; ++s) {
                bf16x8 bg = *(const bf16x8*)&Bl[(s * 16 + l16) * 72 + kk + quad * 8];
                acc[s] = __builtin_amdgcn_mfma_f32_16x16x32_bf16(af, bg, acc[s], 0, 0, 0);
            }
        }
        __syncthreads();
    }

#pragma unroll
    for (int r = 0; r < 4; ++r) {
        int m = wave * 16 + quad * 4 + r;
        int n = nb + l16;
        const float* xr = Xp + m * 2048;
        float iv = acc[0][r] + xr[n];
        float fv = acc[1][r] + xr[512 + n];
        float gv = acc[2][r] + xr[1024 + n];
        float ov = acc[3][r] + xr[1536 + n];
        float cold = c[m * 512 + n];
        float cn = sigf(fv) * cold + sigf(iv) * tanhf(gv);
        float hn = sigf(ov) * tanhf(cn);
        c[m * 512 + n] = cn;
        short hb = f2bf(hn);
        h_out[m * 512 + n] = hb;
        if (dec_idx >= 0)
            dec_h[(size_t)(m * 19 + dec_idx) * 512 + n] = hb;
    }
}

// ---------------------------------------------------------------------------
extern "C" void kernel_launch(void* const* d_in, const int* in_sizes, int n_in,
                              void* d_out, int out_size, void* d_ws, size_t ws_size,
                              hipStream_t stream)
{
    (void)in_sizes; (void)n_in; (void)out_size; (void)ws_size;
    const float* feature   = (const float*)d_in[0];
    const int*   captions  = (const int*)d_in[1];
    const float* embedding = (const float*)d_in[2];
    const float* W_ih      = (const float*)d_in[3];
    const float* W_hh      = (const float*)d_in[4];
    const float* b_ih      = (const float*)d_in[5];
    const float* b_hh      = (const float*)d_in[6];
    const float* W_lin     = (const float*)d_in[7];
    const float* b_lin     = (const float*)d_in[8];
    float* out = (float*)d_out;

    // d_ws: 1.5 MB only
    char* ws = (char*)d_ws;
    short* h0   = (short*)(ws);            // 64*512 bf16 =  65,536 B
    short* h1   = (short*)(ws + 65536);    // 64*512 bf16 =  65,536 B
    float* cc   = (float*)(ws + 131072);   // 64*512 f32  = 131,072 B
    short* dech = (short*)(ws + 262144);   // 1216*512 bf16 = 1,245,184 B -> 1,507,328 total

    // fp32 X_proj lives in d_out (31.5 MB of 155.6 MB); dead before GEMM2.
    float* Xp = (float*)d_out;

    hipMemsetAsync(h0, 0, 65536, stream);   // h(-1) = 0
    hipMemsetAsync(cc, 0, 131072, stream);  // c(-1) = 0

    gemm_xproj<<<dim3(16, 30), 256, 0, stream>>>(
        feature, captions, embedding, W_ih, b_ih, b_hh, Xp);

    // 59 steps (t=59's h never reaches the output: logits[:, :-1])
    for (int t = 0; t < 59; ++t) {
        const short* hi = (t & 1) ? h1 : h0;
        short*       ho = (t & 1) ? h0 : h1;
        lstm_step<<<32, 256, 0, stream>>>(
            Xp + (size_t)t * 131072, W_hh, hi, ho, cc, dech, t - 40);
    }

    // logits = dec_h @ W_lin^T + b_lin  (overwrites all of d_out, incl. Xp)
    gemm_bt<<<dim3(250, 10), 256, 0, stream>>>(
        dech, W_lin, b_lin, out, 1216, 32000, 512);
}

// Round 4
// 1029.884 us; speedup vs baseline: 1.0724x; 1.0724x over previous
//
#include <hip/hip_runtime.h>
#include <hip/hip_bf16.h>

// B=64, T=60 (40 enc + 20 dec), H=512, E=512, V=32000. fp32 I/O.
// Compute: bf16 MFMA (fp32 accum), on-the-fly fp32->bf16 in staging.
//
//   1) gemm_xproj: Xp[3840][2048] = xs @ W_ih^T + (b_ih+b_hh); xs built on the
//      fly (zero-pad | embedding gather | feature). Xp fp32 lives in d_out
//      (dead before GEMM2 overwrites d_out).
//   2) lstm_persist (ONE kernel, 32 blocks): W_hh slice resident in LDS (64KB,
//      loaded once), c in VGPRs, h ping-pong in ws, device-scope counting
//      barrier per step. Writes dec_h (bf16) for t=40..58.
//   3) gemm_out: out[1216][32000] = dec_h @ W_lin^T + b_lin, fp32 out.
//      If ws_size permits, W_lin is pre-converted to bf16 once (cvt_bf16) and
//      GEMM2 stages pure int4; else fallback converts inline.

typedef short bf16x8 __attribute__((ext_vector_type(8)));
typedef float f32x4 __attribute__((ext_vector_type(4)));

__device__ inline short f2bf(float f) {
    unsigned u = __float_as_uint(f);
    unsigned r = (u + 0x7fffu + ((u >> 16) & 1u)) >> 16;   // RNE
    return (short)r;
}
__device__ inline int4 ld8_f32_to_bf16(const float* __restrict__ g) {
    float4 a = *(const float4*)g;
    float4 b = *(const float4*)(g + 4);
    union { short s[8]; int4 v; } u;
    u.s[0] = f2bf(a.x); u.s[1] = f2bf(a.y); u.s[2] = f2bf(a.z); u.s[3] = f2bf(a.w);
    u.s[4] = f2bf(b.x); u.s[5] = f2bf(b.y); u.s[6] = f2bf(b.z); u.s[7] = f2bf(b.w);
    return u.v;
}
__device__ inline float sigf(float x) { return 1.0f / (1.0f + expf(-x)); }

// ---------------------------------------------------------------------------
// GEMM1 (fused xs build): Xp[3840][2048] = xs @ W_ih^T + (b_ih + b_hh), fp32.
// ---------------------------------------------------------------------------
__global__ __launch_bounds__(256) void gemm_xproj(
    const float* __restrict__ feature,    // [64][60][512]
    const int*   __restrict__ captions,   // [64][20]
    const float* __restrict__ embedding,  // [32000][512]
    const float* __restrict__ W_ih,       // [2048][1024]
    const float* __restrict__ b_ih,
    const float* __restrict__ b_hh,
    float* __restrict__ Xp)               // [3840][2048]
{
    __shared__ __align__(16) short Al[128 * 72];
    __shared__ __align__(16) short Bl[128 * 72];
    const int tid  = threadIdx.x;
    const int wave = tid >> 6, lane = tid & 63;
    const int quad = lane >> 4, l16 = lane & 15;
    const int m0 = blockIdx.y * 128;
    const int n0 = blockIdx.x * 128;
    const int wm = (wave >> 1) * 64, wn = (wave & 1) * 64;
    const int sr = tid >> 3;
    const int sc = (tid & 7) * 8;

    f32x4 acc[4][4] = {};

    for (int k0 = 0; k0 < 1024; k0 += 64) {
        const int j = k0 + sc;
#pragma unroll
        for (int p = 0; p < 4; ++p) {
            int r = sr + p * 32;
            int row = m0 + r;
            int t = row >> 6, b = row & 63;
            int4 val;
            if (j < 512) {
                if (t >= 40) {
                    int tok = captions[b * 20 + (t - 40)];
                    val = ld8_f32_to_bf16(&embedding[(size_t)tok * 512 + j]);
                } else {
                    val = make_int4(0, 0, 0, 0);
                }
            } else {
                val = ld8_f32_to_bf16(&feature[(size_t)(b * 60 + t) * 512 + (j - 512)]);
            }
            *(int4*)&Al[r * 72 + sc] = val;
            *(int4*)&Bl[r * 72 + sc] = ld8_f32_to_bf16(&W_ih[(size_t)(n0 + r) * 1024 + j]);
        }
        __syncthreads();
#pragma unroll
        for (int kk = 0; kk < 64; kk += 32) {
            bf16x8 af[4], bg[4];
#pragma unroll
            for (int i = 0; i < 4; ++i)
                af[i] = *(const bf16x8*)&Al[(wm + i * 16 + l16) * 72 + kk + quad * 8];
#pragma unroll
            for (int jj = 0; jj < 4; ++jj)
                bg[jj] = *(const bf16x8*)&Bl[(wn + jj * 16 + l16) * 72 + kk + quad * 8];
#pragma unroll
            for (int i = 0; i < 4; ++i)
#pragma unroll
                for (int jj = 0; jj < 4; ++jj)
                    acc[i][jj] = __builtin_amdgcn_mfma_f32_16x16x32_bf16(
                        af[i], bg[jj], acc[i][jj], 0, 0, 0);
        }
        __syncthreads();
    }

#pragma unroll
    for (int jj = 0; jj < 4; ++jj) {
        int n = n0 + wn + jj * 16 + l16;
        float bv = b_ih[n] + b_hh[n];
#pragma unroll
        for (int i = 0; i < 4; ++i) {
            int mbase = m0 + wm + i * 16 + quad * 4;
#pragma unroll
            for (int r = 0; r < 4; ++r)
                Xp[(size_t)(mbase + r) * 2048 + n] = acc[i][jj][r] + bv;
        }
    }
}

// ---------------------------------------------------------------------------
// W_lin fp32 -> bf16 pre-convert
// ---------------------------------------------------------------------------
__global__ __launch_bounds__(256) void cvt_bf16(
    const float* __restrict__ src, short* __restrict__ dst, int n8)
{
    int i = blockIdx.x * 256 + threadIdx.x;
    if (i < n8)
        *(int4*)&dst[(size_t)i * 8] = ld8_f32_to_bf16(&src[(size_t)i * 8]);
}

// ---------------------------------------------------------------------------
// GEMM2: out[M][N] = A(bf16) @ W[N][K]^T + bias(f32), fp32 out, M-guard.
// BF16B: W already bf16 (pre-converted); else fp32 with inline conversion.
// ---------------------------------------------------------------------------
template <bool BF16B>
__global__ __launch_bounds__(256) void gemm_out(
    const short* __restrict__ A,       // M x K bf16
    const void*  __restrict__ Wv,      // N x K (bf16 or f32)
    const float* __restrict__ bias,    // N
    float* __restrict__ C,
    int M, int N, int K)
{
    __shared__ __align__(16) short Al[128 * 72];
    __shared__ __align__(16) short Bl[128 * 72];
    const int tid  = threadIdx.x;
    const int wave = tid >> 6, lane = tid & 63;
    const int quad = lane >> 4, l16 = lane & 15;
    const int m0 = blockIdx.y * 128;
    const int n0 = blockIdx.x * 128;
    const int wm = (wave >> 1) * 64, wn = (wave & 1) * 64;
    const int sr = tid >> 3;
    const int sc = (tid & 7) * 8;

    f32x4 acc[4][4] = {};

    for (int k0 = 0; k0 < K; k0 += 64) {
#pragma unroll
        for (int p = 0; p < 4; ++p) {
            int r = sr + p * 32;
            int am = m0 + r;
            am = (am < M) ? am : (M - 1);
            *(int4*)&Al[r * 72 + sc] = *(const int4*)&A[(size_t)am * K + k0 + sc];
            if (BF16B)
                *(int4*)&Bl[r * 72 + sc] =
                    *(const int4*)&((const short*)Wv)[(size_t)(n0 + r) * K + k0 + sc];
            else
                *(int4*)&Bl[r * 72 + sc] =
                    ld8_f32_to_bf16(&((const float*)Wv)[(size_t)(n0 + r) * K + k0 + sc]);
        }
        __syncthreads();
#pragma unroll
        for (int kk = 0; kk < 64; kk += 32) {
            bf16x8 af[4], bg[4];
#pragma unroll
            for (int i = 0; i < 4; ++i)
                af[i] = *(const bf16x8*)&Al[(wm + i * 16 + l16) * 72 + kk + quad * 8];
#pragma unroll
            for (int jj = 0; jj < 4; ++jj)
                bg[jj] = *(const bf16x8*)&Bl[(wn + jj * 16 + l16) * 72 + kk + quad * 8];
#pragma unroll
            for (int i = 0; i < 4; ++i)
#pragma unroll
                for (int jj = 0; jj < 4; ++jj)
                    acc[i][jj] = __builtin_amdgcn_mfma_f32_16x16x32_bf16(
                        af[i], bg[jj], acc[i][jj], 0, 0, 0);
        }
        __syncthreads();
    }

#pragma unroll
    for (int jj = 0; jj < 4; ++jj) {
        int n = n0 + wn + jj * 16 + l16;
        float bv = bias[n];
#pragma unroll
        for (int i = 0; i < 4; ++i) {
            int mbase = m0 + wm + i * 16 + quad * 4;
#pragma unroll
            for (int r = 0; r < 4; ++r) {
                int m = mbase + r;
                if (m < M)
                    C[(size_t)m * N + n] = acc[i][jj][r] + bv;
            }
        }
    }
}

// ---------------------------------------------------------------------------
// Persistent LSTM: 32 blocks x 256 thr. Block bx owns h-cols [16bx,16bx+16)
// (i.e. gate-cols {s*512+16bx..} for s=0..3). W_hh slice (64 rows x 512 K,
// bf16) lives in LDS, loaded once. c lives in VGPRs. h ping-pongs in global
// (bf16). Device-scope counting barrier between steps (per-step counter).
// Wave w handles batch rows 16w..16w+15; gates i,f,g,o mixed in-register.
// ---------------------------------------------------------------------------
#define LSTM_BLOCKS 32

__global__ __launch_bounds__(256) void lstm_persist(
    const float* __restrict__ Xp,     // [59][64][2048] fp32 (in d_out)
    const float* __restrict__ W_hh,   // [2048][512] fp32
    short* __restrict__ hbuf,         // [2][64][512] bf16 ping-pong
    short* __restrict__ dec_h,        // [1216][512] bf16 (row = b*19 + dec)
    unsigned* __restrict__ bar)       // [64] zeroed per launch
{
    __shared__ __align__(16) short Wl[64 * 512];   // exactly 64 KB
    const int tid  = threadIdx.x;
    const int wave = tid >> 6, lane = tid & 63;
    const int quad = lane >> 4, l16 = lane & 15;
    const int nb = blockIdx.x * 16;

    // one-time: W slice -> LDS (row rr = s*16+col <-> W_hh row s*512+nb+col)
#pragma unroll
    for (int it = 0; it < 16; ++it) {
        int rr = (tid >> 6) + it * 4;          // 0..63
        int k  = (tid & 63) * 8;               // 0..504
        int s = rr >> 4, col = rr & 15;
        *(int4*)&Wl[rr * 512 + k] =
            ld8_f32_to_bf16(&W_hh[(size_t)(s * 512 + nb + col) * 512 + k]);
    }
    float creg[4] = {0.f, 0.f, 0.f, 0.f};
    __syncthreads();

    for (int t = 0; t < 59; ++t) {
        f32x4 acc[4] = {};
        if (t > 0) {
            const short* hin = hbuf + (((t & 1) ^ 1) << 15);
            const short* hrow = &hin[(wave * 16 + l16) * 512 + quad * 8];
            bf16x8 hf[16];
#pragma unroll
            for (int kk = 0; kk < 16; ++kk)
                hf[kk] = *(const bf16x8*)&hrow[kk * 32];
#pragma unroll
            for (int kk = 0; kk < 16; ++kk) {
#pragma unroll
                for (int s = 0; s < 4; ++s) {
                    bf16x8 bg = *(const bf16x8*)&Wl[(s * 16 + l16) * 512 + kk * 32 + quad * 8];
                    acc[s] = __builtin_amdgcn_mfma_f32_16x16x32_bf16(hf[kk], bg, acc[s], 0, 0, 0);
                }
            }
        }
        // cell update (C-layout: row = quad*4+r, col = l16)
        const float* xt = Xp + (size_t)t * 131072;
        short* hout = hbuf + ((t & 1) << 15);
        const int n = nb + l16;
#pragma unroll
        for (int r = 0; r < 4; ++r) {
            int m = wave * 16 + quad * 4 + r;
            const float* xr = xt + m * 2048;
            float iv = acc[0][r] + xr[n];
            float fv = acc[1][r] + xr[512 + n];
            float gv = acc[2][r] + xr[1024 + n];
            float ov = acc[3][r] + xr[1536 + n];
            float cn = sigf(fv) * creg[r] + sigf(iv) * tanhf(gv);
            float hn = sigf(ov) * tanhf(cn);
            creg[r] = cn;
            short hb = f2bf(hn);
            hout[m * 512 + n] = hb;
            if (t >= 40)
                dec_h[(size_t)(m * 19 + (t - 40)) * 512 + n] = hb;
        }
        if (t < 58) {
            __syncthreads();                    // drains vmcnt for all waves
            if (tid == 0) {
                __threadfence();                // release: writeback local L2
                __hip_atomic_fetch_add(&bar[t], 1u, __ATOMIC_RELEASE,
                                       __HIP_MEMORY_SCOPE_AGENT);
                while (__hip_atomic_load(&bar[t], __ATOMIC_ACQUIRE,
                                         __HIP_MEMORY_SCOPE_AGENT) < LSTM_BLOCKS) {
                    __builtin_amdgcn_s_sleep(1);
                }
            }
            __syncthreads();
            __threadfence();                    // acquire: invalidate stale caches
        }
    }
}

// ---------------------------------------------------------------------------
extern "C" void kernel_launch(void* const* d_in, const int* in_sizes, int n_in,
                              void* d_out, int out_size, void* d_ws, size_t ws_size,
                              hipStream_t stream)
{
    (void)in_sizes; (void)n_in; (void)out_size;
    const float* feature   = (const float*)d_in[0];
    const int*   captions  = (const int*)d_in[1];
    const float* embedding = (const float*)d_in[2];
    const float* W_ih      = (const float*)d_in[3];
    const float* W_hh      = (const float*)d_in[4];
    const float* b_ih      = (const float*)d_in[5];
    const float* b_hh      = (const float*)d_in[6];
    const float* W_lin     = (const float*)d_in[7];
    const float* b_lin     = (const float*)d_in[8];
    float* out = (float*)d_out;

    // ws layout
    char* ws = (char*)d_ws;
    short*    hbuf = (short*)(ws);                 // 2*64*512*2   = 131,072 B
    short*    dech = (short*)(ws + 131072);        // 1216*512*2   = 1,245,184 B
    unsigned* bar  = (unsigned*)(ws + 1376256);    // 256 B
    short*    wbf  = (short*)(ws + 1376512);       // 32000*512*2  = 32,768,000 B
    const bool big = ws_size >= (size_t)1376512 + 32768000;

    // fp32 X_proj lives in d_out (31.5 MB of 155.6 MB); dead before GEMM2.
    float* Xp = (float*)d_out;

    hipMemsetAsync(bar, 0, 256, stream);

    if (big)
        cvt_bf16<<<8000, 256, 0, stream>>>(W_lin, wbf, 2048000);

    gemm_xproj<<<dim3(16, 30), 256, 0, stream>>>(
        feature, captions, embedding, W_ih, b_ih, b_hh, Xp);

    lstm_persist<<<LSTM_BLOCKS, 256, 0, stream>>>(Xp, W_hh, hbuf, dech, bar);

    if (big)
        gemm_out<true><<<dim3(250, 10), 256, 0, stream>>>(
            dech, wbf, b_lin, out, 1216, 32000, 512);
    else
        gemm_out<false><<<dim3(250, 10), 256, 0, stream>>>(
            dech, W_lin, b_lin, out, 1216, 32000, 512);
}